// Round 12
// baseline (428.333 us; speedup 1.0000x reference)
//
#include <hip/hip_runtime.h>

#define N_NODES 50000
#define N_EDGES 800000
#define NF 128   // node feature dim
#define EH 32    // edge hidden
#define ROWS 32  // node rows per block (tile height)

typedef __bf16 bf16x8 __attribute__((ext_vector_type(8)));
typedef float f32x4 __attribute__((ext_vector_type(4)));
typedef unsigned short u16x8 __attribute__((ext_vector_type(8)));
typedef unsigned short ushort_t;
typedef unsigned int uint_t;

__device__ inline ushort_t f2bf(float x) {
  uint_t u = __builtin_bit_cast(uint_t, x);
  return (ushort_t)((u + 0x7fffu + ((u >> 16) & 1u)) >> 16);
}
__device__ inline float blo(uint_t u) { return __builtin_bit_cast(float, u << 16); }
__device__ inline float bhi(uint_t u) { return __builtin_bit_cast(float, u & 0xffff0000u); }

// ---------------- prep + input cast + per-node degree histogram -------------
// blocks [0,448): weight prep; [448,6698): input cast; [6698,9823): degree
// histogram via global atomics (deg[] pre-zeroed by hipMemsetAsync).
__global__ __launch_bounds__(256) void k_prep(
    const float* __restrict__ ws1, const float* __restrict__ wn1,
    const float* __restrict__ ws2, const float* __restrict__ wn2,
    const float* __restrict__ ws3, const float* __restrict__ wn3,
    const float* __restrict__ wu1, const float* __restrict__ wv1,
    const float* __restrict__ wu2, const float* __restrict__ wv2,
    ushort_t* __restrict__ wt1, ushort_t* __restrict__ wt2, ushort_t* __restrict__ wt3,
    ushort_t* __restrict__ wp1, ushort_t* __restrict__ wp2,
    const float* __restrict__ x, ushort_t* __restrict__ xb,
    const int* __restrict__ edst, int* __restrict__ deg) {
  int blk = blockIdx.x;
  int t = threadIdx.x;
  if (blk < 448) {  // weight prep (114688 items)
    int i = blk * 256 + t;
    if (i < 98304) {
      int l = i >> 15;
      int j = i & 32767;
      int n = j >> 8, k = j & 255;
      const float* s = (l == 0) ? (k < 128 ? ws1 : wn1)
                     : (l == 1) ? (k < 128 ? ws2 : wn2)
                                : (k < 128 ? ws3 : wn3);
      float v = s[(k & 127) * 128 + n];
      ushort_t* d = (l == 0) ? wt1 : (l == 1) ? wt2 : wt3;
      d[n * 256 + k] = f2bf(v);
    } else if (i < 114688) {
      int j = i - 98304;
      int l = j >> 13;
      int m = j & 8191;
      int n = m >> 7, k = m & 127;
      const float* s = (l == 0) ? (n < 32 ? wu1 : wv1) : (n < 32 ? wu2 : wv2);
      float v = s[k * 32 + (n & 31)];
      ushort_t* d = (l == 0) ? wp1 : wp2;
      d[n * 128 + k] = f2bf(v);
    }
  } else if (blk < 6698) {  // input cast: 1.6M float4 groups / 6250 blocks
    int i = (blk - 448) * 256 + t;
    float4 v = ((const float4*)x)[i];
    uint2 p;
    p.x = (uint_t)f2bf(v.x) | ((uint_t)f2bf(v.y) << 16);
    p.y = (uint_t)f2bf(v.z) | ((uint_t)f2bf(v.w) << 16);
    ((uint2*)xb)[i] = p;
  } else {  // degree histogram: 3125 blocks x 256 edges
    int i = (blk - 6698) * 256 + t;
    atomicAdd(&deg[edst[i]], 1);
  }
}

// s1: 196 blocks; block-local exclusive scan of deg (in place) + block totals
__global__ __launch_bounds__(256) void s1_scan(int* __restrict__ g,
                                               int* __restrict__ btot) {
  __shared__ int wpart[4];
  int t = threadIdx.x, lane = t & 63;
  int i = blockIdx.x * 256 + t;
  int v = g[i];
  int x = v;
  #pragma unroll
  for (int off = 1; off < 64; off <<= 1) {
    int y = __shfl_up(x, off, 64);
    if (lane >= off) x += y;
  }
  if (lane == 63) wpart[t >> 6] = x;
  __syncthreads();
  int wo = 0;
  #pragma unroll
  for (int w = 0; w < 4; ++w)
    if (w < (t >> 6)) wo += wpart[w];
  g[i] = wo + x - v;               // local exclusive
  if (t == 255) btot[blockIdx.x] = wo + x;  // block total
}

// s2: 196 blocks; each redundantly scans the 196 block totals, then finalizes
// its 256 rowptr entries: rowptr[n] = rloc[n] + sofs[block].
__global__ __launch_bounds__(256) void s2_final(const int* __restrict__ rloc,
                                                const int* __restrict__ btot,
                                                int* __restrict__ rowptr) {
  __shared__ int wpart[4];
  __shared__ int sofs[256];
  int t = threadIdx.x, lane = t & 63;
  int v = (t < 196) ? btot[t] : 0;
  int x = v;
  #pragma unroll
  for (int off = 1; off < 64; off <<= 1) {
    int y = __shfl_up(x, off, 64);
    if (lane >= off) x += y;
  }
  if (lane == 63) wpart[t >> 6] = x;
  __syncthreads();
  int wo = 0;
  #pragma unroll
  for (int w = 0; w < 4; ++w)
    if (w < (t >> 6)) wo += wpart[w];
  sofs[t] = wo + x - v;
  __syncthreads();
  int n = blockIdx.x * 256 + t;
  if (n <= N_NODES) rowptr[n] = rloc[n] + sofs[blockIdx.x];
}

// scatter: one edge per thread; cnt[] pre-zeroed by the memset.
__global__ __launch_bounds__(256) void k_scatter(const int* __restrict__ esrc,
                                                 const int* __restrict__ edst,
                                                 const int* __restrict__ rowptr,
                                                 int* __restrict__ cnt,
                                                 int* __restrict__ csr_src) {
  int e = blockIdx.x * 256 + threadIdx.x;
  int d = edst[e];
  int s = esrc[e];
  int p = rowptr[d] + atomicAdd(&cnt[d], 1);
  csr_src[p] = s;
}

// ---------------- merged: fused SAGE (blocks < gsage) + edge MLP (rest) -----
template <int EFD>
__global__ __launch_bounds__(256) void k_merged(
    // sage args
    const ushort_t* __restrict__ hb,
    const int* __restrict__ rowptr, const int* __restrict__ csr_src,
    const ushort_t* __restrict__ wt, const float* __restrict__ bias,
    ushort_t* __restrict__ out_bf, float* __restrict__ out_f32,
    const ushort_t* __restrict__ wp,
    ushort_t* __restrict__ hub_o, ushort_t* __restrict__ hvb_o,
    int M, int do_relu, int gsage,
    // edge args
    const ushort_t* __restrict__ hub_i, const ushort_t* __restrict__ hvb_i,
    const int* __restrict__ src, const int* __restrict__ dst,
    const float* __restrict__ ef1, const float* __restrict__ ef2,
    const float* __restrict__ we, const float* __restrict__ b,
    const float* __restrict__ w2, const float* __restrict__ b2,
    float* __restrict__ eout, int E) {
  __shared__ ushort_t hs[ROWS][136];
  __shared__ float swe[EFD][EH];
  __shared__ float sw2t[4][EH];
  __shared__ float sb[EH];
  __shared__ float sb2v[4];
  int tid = threadIdx.x;

  if ((int)blockIdx.x >= gsage) {
    // ================= edge part =================
    for (int i = tid; i < EFD * EH; i += 256) swe[i >> 5][i & 31] = we[i];
    if (tid < EH * 4) sw2t[tid & 3][tid >> 2] = w2[tid];
    if (tid < EH) sb[tid] = b[tid];
    if (tid < 4) sb2v[tid] = b2[tid];
    __syncthreads();
    int gi = (blockIdx.x - gsage) * 256 + tid;
    int e = gi >> 2;
    int q = gi & 3;
    if (e >= E) return;
    int s = src[e], d = dst[e];
    int cb = q * 8;
    uint4 au = *(const uint4*)&hub_i[s * EH + cb];
    uint4 av = *(const uint4*)&hvb_i[d * EH + cb];
    float efv[EFD];
    {
      float4 v = *(const float4*)&ef1[(long long)e * 4];
      efv[0] = v.x; efv[1] = v.y; efv[2] = v.z; efv[3] = v.w;
      if constexpr (EFD == 8) {
        float4 v1 = *(const float4*)&ef2[(long long)e * 4];
        efv[4] = v1.x; efv[5] = v1.y; efv[6] = v1.z; efv[7] = v1.w;
      }
    }
    float t[8];
    t[0] = blo(au.x) + blo(av.x) + sb[cb + 0];
    t[1] = bhi(au.x) + bhi(av.x) + sb[cb + 1];
    t[2] = blo(au.y) + blo(av.y) + sb[cb + 2];
    t[3] = bhi(au.y) + bhi(av.y) + sb[cb + 3];
    t[4] = blo(au.z) + blo(av.z) + sb[cb + 4];
    t[5] = bhi(au.z) + bhi(av.z) + sb[cb + 5];
    t[6] = blo(au.w) + blo(av.w) + sb[cb + 6];
    t[7] = bhi(au.w) + bhi(av.w) + sb[cb + 7];
    #pragma unroll
    for (int i = 0; i < EFD; ++i) {
      float efi = efv[i];
      #pragma unroll
      for (int j = 0; j < 8; ++j) t[j] += efi * swe[i][cb + j];
    }
    #pragma unroll
    for (int j = 0; j < 8; ++j) t[j] = fmaxf(t[j], 0.f);
    float o0 = 0.f, o1 = 0.f, o2 = 0.f, o3 = 0.f;
    #pragma unroll
    for (int j = 0; j < 8; ++j) {
      o0 += t[j] * sw2t[0][cb + j];
      o1 += t[j] * sw2t[1][cb + j];
      o2 += t[j] * sw2t[2][cb + j];
      o3 += t[j] * sw2t[3][cb + j];
    }
    #pragma unroll
    for (int m = 2; m; m >>= 1) {
      o0 += __shfl_xor(o0, m, 64);
      o1 += __shfl_xor(o1, m, 64);
      o2 += __shfl_xor(o2, m, 64);
      o3 += __shfl_xor(o3, m, 64);
    }
    if constexpr (EFD == 4) {
      if (q == 0)
        *(float4*)&eout[(long long)e * 4] =
            make_float4(o0 + sb2v[0], o1 + sb2v[1], o2 + sb2v[2], o3 + sb2v[3]);
    } else {
      if (q == 0)
        *(float4*)&eout[(long long)e * 12 + 8] =
            make_float4(o0 + sb2v[0], o1 + sb2v[1], o2 + sb2v[2], o3 + sb2v[3]);
      if (q == 1)
        *(float4*)&eout[(long long)e * 12] =
            make_float4(efv[0], efv[1], efv[2], efv[3]);
      if (q == 2)
        *(float4*)&eout[(long long)e * 12 + 4] =
            make_float4(efv[4], efv[5], efv[6], efv[7]);
    }
    return;
  }

  // ================= sage part =================
  int wave = tid >> 6, lane = tid & 63;
  int l16 = lane & 15, quad = lane >> 4;
  int row0 = blockIdx.x * ROWS;

  // ---- Phase G: 2 rounds x 4 concurrent nodes per wave, 4-deep ILP
  {
    int grp = lane >> 4;   // node slot 0..3
    int l16g = lane & 15;  // 16B chunk within the 256B row
    #pragma unroll
    for (int r = 0; r < 2; ++r) {
      int lr = wave * 8 + r * 4 + grp;  // local row 0..31
      int n = row0 + lr;
      int beg = 0, end = 0;
      if (n < M) { beg = rowptr[n]; end = rowptr[n + 1]; }
      float f[8];
      #pragma unroll
      for (int k = 0; k < 8; ++k) f[k] = 0.f;
      int j = beg;
      for (; j + 4 <= end; j += 4) {  // 4-deep ILP, no cross-lane deps
        int s0 = csr_src[j];
        int s1 = csr_src[j + 1];
        int s2 = csr_src[j + 2];
        int s3 = csr_src[j + 3];
        uint4 a = *(const uint4*)&hb[s0 * NF + l16g * 8];
        uint4 bb = *(const uint4*)&hb[s1 * NF + l16g * 8];
        uint4 c = *(const uint4*)&hb[s2 * NF + l16g * 8];
        uint4 d = *(const uint4*)&hb[s3 * NF + l16g * 8];
        f[0] += blo(a.x) + blo(bb.x) + blo(c.x) + blo(d.x);
        f[1] += bhi(a.x) + bhi(bb.x) + bhi(c.x) + bhi(d.x);
        f[2] += blo(a.y) + blo(bb.y) + blo(c.y) + blo(d.y);
        f[3] += bhi(a.y) + bhi(bb.y) + bhi(c.y) + bhi(d.y);
        f[4] += blo(a.z) + blo(bb.z) + blo(c.z) + blo(d.z);
        f[5] += bhi(a.z) + bhi(bb.z) + bhi(c.z) + bhi(d.z);
        f[6] += blo(a.w) + blo(bb.w) + blo(c.w) + blo(d.w);
        f[7] += bhi(a.w) + bhi(bb.w) + bhi(c.w) + bhi(d.w);
      }
      for (; j < end; ++j) {  // scalar tail
        int s0 = csr_src[j];
        uint4 a = *(const uint4*)&hb[s0 * NF + l16g * 8];
        f[0] += blo(a.x); f[1] += bhi(a.x);
        f[2] += blo(a.y); f[3] += bhi(a.y);
        f[4] += blo(a.z); f[5] += bhi(a.z);
        f[6] += blo(a.w); f[7] += bhi(a.w);
      }
      if (n < M) {
        int deg = end - beg;
        float inv = deg > 0 ? 1.0f / (float)deg : 0.f;
        u16x8 p;
        #pragma unroll
        for (int k = 0; k < 8; ++k) p[k] = f2bf(f[k] * inv);
        *(u16x8*)&hs[lr][l16g * 8] = p;
      }
    }
  }
  __syncthreads();

  // ---- Phase M: MFMA over K=256 ([self(global) | agg(LDS)])
  int n0 = wave * 32;
  f32x4 acc[2][2];
  #pragma unroll
  for (int a = 0; a < 2; ++a)
    #pragma unroll
    for (int b2_ = 0; b2_ < 2; ++b2_) acc[a][b2_] = (f32x4){0.f, 0.f, 0.f, 0.f};

  #pragma unroll
  for (int ks = 0; ks < 8; ++ks) {
    int k0 = ks * 32;
    bf16x8 afr[2];
    #pragma unroll
    for (int mt = 0; mt < 2; ++mt) {
      if (ks < 4) {
        int r = row0 + mt * 16 + l16;
        if (r >= M) r = M - 1;
        afr[mt] = __builtin_bit_cast(bf16x8, *(const u16x8*)&hb[r * NF + k0 + quad * 8]);
      } else {
        afr[mt] = __builtin_bit_cast(bf16x8,
            *(const u16x8*)&hs[mt * 16 + l16][(k0 & 127) + quad * 8]);
      }
    }
    bf16x8 bfr[2];
    #pragma unroll
    for (int nt = 0; nt < 2; ++nt) {
      int n = n0 + nt * 16 + l16;
      bfr[nt] = __builtin_bit_cast(bf16x8, *(const u16x8*)&wt[n * 256 + k0 + quad * 8]);
    }
    #pragma unroll
    for (int mt = 0; mt < 2; ++mt)
      #pragma unroll
      for (int nt = 0; nt < 2; ++nt)
        acc[mt][nt] = __builtin_amdgcn_mfma_f32_16x16x32_bf16(
            afr[mt], bfr[nt], acc[mt][nt], 0, 0, 0);
  }

  if (wp) __syncthreads();  // all waves done reading agg LDS before overwrite

  #pragma unroll
  for (int nt = 0; nt < 2; ++nt) {
    int col = n0 + nt * 16 + l16;
    float bv = bias[col];
    #pragma unroll
    for (int mt = 0; mt < 2; ++mt) {
      #pragma unroll
      for (int reg = 0; reg < 4; ++reg) {
        int lr = mt * 16 + quad * 4 + reg;
        int r = row0 + lr;
        float v = acc[mt][nt][reg] + bv;
        if (do_relu) v = fmaxf(v, 0.f);
        if (r < M) {
          if (out_f32) out_f32[r * NF + col] = v;
          else         out_bf[r * NF + col] = f2bf(v);
        }
        if (wp) hs[lr][col] = f2bf(v);  // rows >= M hold junk; never stored later
      }
    }
  }

  if (wp) {
    __syncthreads();
    int nb2 = wave * 16;
    f32x4 pacc[2];
    #pragma unroll
    for (int a = 0; a < 2; ++a) pacc[a] = (f32x4){0.f, 0.f, 0.f, 0.f};
    #pragma unroll
    for (int ks = 0; ks < 4; ++ks) {
      int k0 = ks * 32;
      bf16x8 bfrp = __builtin_bit_cast(bf16x8,
          *(const u16x8*)&wp[(nb2 + l16) * NF + k0 + quad * 8]);
      #pragma unroll
      for (int mt = 0; mt < 2; ++mt) {
        bf16x8 afr = __builtin_bit_cast(bf16x8,
            *(const u16x8*)&hs[mt * 16 + l16][k0 + quad * 8]);
        pacc[mt] = __builtin_amdgcn_mfma_f32_16x16x32_bf16(afr, bfrp, pacc[mt], 0, 0, 0);
      }
    }
    int col = nb2 + l16;
    #pragma unroll
    for (int mt = 0; mt < 2; ++mt) {
      #pragma unroll
      for (int reg = 0; reg < 4; ++reg) {
        int r = row0 + mt * 16 + quad * 4 + reg;
        if (r < M) {
          ushort_t v = f2bf(pacc[mt][reg]);
          if (col < 32) hub_o[r * EH + col] = v;
          else          hvb_o[r * EH + col - 32] = v;
        }
      }
    }
  }
}

// ---------------- launch ----------------
extern "C" void kernel_launch(void* const* d_in, const int* in_sizes, int n_in,
                              void* d_out, int out_size, void* d_ws, size_t ws_size,
                              hipStream_t stream) {
  const float* inputs    = (const float*)d_in[0];
  const float* edge_feat = (const float*)d_in[1];
  const float* w_self1   = (const float*)d_in[2];
  const float* w_neigh1  = (const float*)d_in[3];
  const float* b_conv1   = (const float*)d_in[4];
  const float* eu1_wu    = (const float*)d_in[5];
  const float* eu1_wv    = (const float*)d_in[6];
  const float* eu1_we    = (const float*)d_in[7];
  const float* eu1_b     = (const float*)d_in[8];
  const float* eu1_w2    = (const float*)d_in[9];
  const float* eu1_b2    = (const float*)d_in[10];
  const float* w_self2   = (const float*)d_in[11];
  const float* w_neigh2  = (const float*)d_in[12];
  const float* b_conv2   = (const float*)d_in[13];
  const float* eu2_wu    = (const float*)d_in[14];
  const float* eu2_wv    = (const float*)d_in[15];
  const float* eu2_we    = (const float*)d_in[16];
  const float* eu2_b     = (const float*)d_in[17];
  const float* eu2_w2    = (const float*)d_in[18];
  const float* eu2_b2    = (const float*)d_in[19];
  const float* w_self3   = (const float*)d_in[20];
  const float* w_neigh3  = (const float*)d_in[21];
  const float* b_conv3   = (const float*)d_in[22];
  const int*   esrc      = (const int*)d_in[23];
  const int*   edst      = (const int*)d_in[24];

  float* out_h  = (float*)d_out;                           // [N,128]
  float* out_ef = (float*)d_out + (long long)N_NODES * NF; // [E,12]

  // workspace: int region then bf16 region
  int* iws     = (int*)d_ws;
  int* deg     = iws;                 // 50176 (rloc in place after s1)
  int* btot    = iws + 50176;         // 256 (196 used)
  int* cnt     = iws + 50432;         // 50176 -> ends 100608 (memset region)
  int* rowptr  = iws + 832768;        // 50001 (pad 50004) -> ends 882772
  int* csr_src = iws + 882784;        // 800000 -> ends 1682784
  ushort_t* ub = (ushort_t*)(iws + 1682784);  // byte off 6731136, %16==0
  ushort_t* xb   = ub;                        // N*128 = 6.4e6
  ushort_t* hAb  = ub + 6400000;
  ushort_t* hBb  = ub + 12800000;
  // compact eu1 staging [E,4] fp32 in the free ex-aggb slot (12.8MB)
  float* eu1t    = (float*)(ub + 19200000);   // 6.4e6 ushorts = 12.8MB
  ushort_t* wt1  = ub + 25600000;             // 32768 each
  ushort_t* wt2  = ub + 25632768;
  ushort_t* wt3  = ub + 25665536;
  ushort_t* wp1  = ub + 25698304;             // 8192 each
  ushort_t* wp2  = ub + 25706496;             // ends 25714688
  // hu/hv layer1: dedicated (no aliasing — sage2 runs concurrently w/ edge1)
  ushort_t* hub1 = ub + 25714688;             // 1.6e6 each
  ushort_t* hvb1 = ub + 27314688;             // ends 28914688
  // hu/hv layer2 alias xb (xb dead after sage1 reads it)
  ushort_t* hub2 = xb;
  ushort_t* hvb2 = xb + (long long)N_NODES * EH;

  const int N = N_NODES, E = N_EDGES;
  int gsage = (N + ROWS - 1) / ROWS;          // 1563
  int gedge = (E * 4) / 256;                  // 12500 exactly
  int gmerged = gsage + gedge;                // 14063

  // ---- zero deg + cnt (402KB), then prep(+hist), scan, finalize, scatter
  hipMemsetAsync(iws, 0, 100608 * sizeof(int), stream);
  k_prep<<<448 + 6250 + 3125, 256, 0, stream>>>(
      w_self1, w_neigh1, w_self2, w_neigh2, w_self3, w_neigh3,
      eu1_wu, eu1_wv, eu2_wu, eu2_wv,
      wt1, wt2, wt3, wp1, wp2, inputs, xb, edst, deg);
  s1_scan<<<196, 256, 0, stream>>>(deg, btot);
  s2_final<<<196, 256, 0, stream>>>(deg, btot, rowptr);
  k_scatter<<<3125, 256, 0, stream>>>(esrc, edst, rowptr, cnt, csr_src);

  // ---- layer 1 sage (sage-only launch: grid == gsage, edge part idle)
  k_merged<4><<<gsage, 256, 0, stream>>>(
      xb, rowptr, csr_src, wt1, b_conv1, hAb, nullptr, wp1, hub1, hvb1,
      N, 1, gsage,
      nullptr, nullptr, nullptr, nullptr, nullptr, nullptr,
      nullptr, nullptr, nullptr, nullptr, nullptr, 0);

  // ---- edge1 (eu1 -> eu1t) || sage2 (hAb -> hBb, proj -> hub2/hvb2)
  k_merged<4><<<gmerged, 256, 0, stream>>>(
      hAb, rowptr, csr_src, wt2, b_conv2, hBb, nullptr, wp2, hub2, hvb2,
      N, 1, gsage,
      hub1, hvb1, esrc, edst, edge_feat, nullptr,
      eu1_we, eu1_b, eu1_w2, eu1_b2, eu1t, E);

  // ---- edge2 (full out_ef rows) || sage3 (hBb -> out_h fp32, no proj)
  k_merged<8><<<gmerged, 256, 0, stream>>>(
      hBb, rowptr, csr_src, wt3, b_conv3, nullptr, out_h, nullptr, nullptr, nullptr,
      N, 0, gsage,
      hub2, hvb2, esrc, edst, edge_feat, eu1t,
      eu2_we, eu2_b, eu2_w2, eu2_b2, out_ef, E);
}

// Round 13
// 377.529 us; speedup vs baseline: 1.1346x; 1.1346x over previous
//
#include <hip/hip_runtime.h>

#define N_NODES 50000
#define N_EDGES 800000
#define NF 128   // node feature dim
#define EH 32    // edge hidden
#define NB 128   // dst buckets for CSR sort
#define BN 391   // nodes per bucket (128*391 = 50048 >= 50000)
#define NCH 256  // edge chunks
#define CE 3125  // edges per chunk (256*3125 = 800000 exactly)
#define ROWS 32  // node rows per block (tile height)

typedef __bf16 bf16x8 __attribute__((ext_vector_type(8)));
typedef float f32x4 __attribute__((ext_vector_type(4)));
typedef unsigned short u16x8 __attribute__((ext_vector_type(8)));
typedef unsigned short ushort_t;
typedef unsigned int uint_t;

__device__ inline ushort_t f2bf(float x) {
  uint_t u = __builtin_bit_cast(uint_t, x);
  return (ushort_t)((u + 0x7fffu + ((u >> 16) & 1u)) >> 16);
}
__device__ inline float blo(uint_t u) { return __builtin_bit_cast(float, u << 16); }
__device__ inline float bhi(uint_t u) { return __builtin_bit_cast(float, u & 0xffff0000u); }

// ---------------- prep + input cast + f1 histogram (merged) ----------------
__global__ __launch_bounds__(256) void k_prep(
    const float* __restrict__ ws1, const float* __restrict__ wn1,
    const float* __restrict__ ws2, const float* __restrict__ wn2,
    const float* __restrict__ ws3, const float* __restrict__ wn3,
    const float* __restrict__ wu1, const float* __restrict__ wv1,
    const float* __restrict__ wu2, const float* __restrict__ wv2,
    ushort_t* __restrict__ wt1, ushort_t* __restrict__ wt2, ushort_t* __restrict__ wt3,
    ushort_t* __restrict__ wp1, ushort_t* __restrict__ wp2,
    const float* __restrict__ x, ushort_t* __restrict__ xb,
    const int* __restrict__ edst, int* __restrict__ ghist) {
  __shared__ int h[NB];
  int blk = blockIdx.x;
  int t = threadIdx.x;
  if (blk < 448) {  // weight prep (114688 items)
    int i = blk * 256 + t;
    if (i < 98304) {
      int l = i >> 15;
      int j = i & 32767;
      int n = j >> 8, k = j & 255;
      const float* s = (l == 0) ? (k < 128 ? ws1 : wn1)
                     : (l == 1) ? (k < 128 ? ws2 : wn2)
                                : (k < 128 ? ws3 : wn3);
      float v = s[(k & 127) * 128 + n];
      ushort_t* d = (l == 0) ? wt1 : (l == 1) ? wt2 : wt3;
      d[n * 256 + k] = f2bf(v);
    } else if (i < 114688) {
      int j = i - 98304;
      int l = j >> 13;
      int m = j & 8191;
      int n = m >> 7, k = m & 127;
      const float* s = (l == 0) ? (n < 32 ? wu1 : wv1) : (n < 32 ? wu2 : wv2);
      float v = s[k * 32 + (n & 31)];
      ushort_t* d = (l == 0) ? wp1 : wp2;
      d[n * 128 + k] = f2bf(v);
    }
  } else if (blk < 6698) {  // input cast: 1.6M float4 groups / 6250 blocks
    int i = (blk - 448) * 256 + t;
    float4 v = ((const float4*)x)[i];
    uint2 p;
    p.x = (uint_t)f2bf(v.x) | ((uint_t)f2bf(v.y) << 16);
    p.y = (uint_t)f2bf(v.z) | ((uint_t)f2bf(v.w) << 16);
    ((uint2*)xb)[i] = p;
  } else {  // f1 histogram: 256 chunks
    int c = blk - 6698;
    if (t < NB) h[t] = 0;
    __syncthreads();
    int base = c * CE;
    for (int i = t; i < CE; i += 256) atomicAdd(&h[edst[base + i] / BN], 1);
    __syncthreads();
    if (t < NB) ghist[t * NCH + c] = h[t];  // bucket-major
  }
}

// f2b: 128 blocks, each local-exclusive-scans one bucket's 256 chunk counts
// and emits the bucket total. (No single-block serialization; the 128-wide
// exclusive scan of totals is recomputed redundantly inside f3/f4.)
__global__ __launch_bounds__(256) void f2b_scan(int* __restrict__ g,
                                                int* __restrict__ btot) {
  __shared__ int wpart[4];
  int t = threadIdx.x, lane = t & 63;
  int b = blockIdx.x;
  int i = b * 256 + t;
  int v = g[i];
  int x = v;
  #pragma unroll
  for (int off = 1; off < 64; off <<= 1) {
    int y = __shfl_up(x, off, 64);
    if (lane >= off) x += y;
  }
  if (lane == 63) wpart[t >> 6] = x;
  __syncthreads();
  int wo = 0;
  #pragma unroll
  for (int w = 0; w < 4; ++w)
    if (w < (t >> 6)) wo += wpart[w];
  g[i] = wo + x - v;               // local exclusive within bucket
  if (t == 255) btot[b] = wo + x;  // bucket total
}

// f3: bin packed (dst<<16|src) edges into bucket-major ebuf.
// Computes the 128-wide exclusive bucket-offset scan redundantly per block.
__global__ __launch_bounds__(256) void f3_bin(const int* __restrict__ esrc,
                                              const int* __restrict__ edst,
                                              const int* __restrict__ g,
                                              const int* __restrict__ btot,
                                              uint_t* __restrict__ ebuf) {
  __shared__ int cur[NB];
  __shared__ int wtot[2];
  int t = threadIdx.x, c = blockIdx.x;
  int lane = t & 63;
  int x = 0, v = 0;
  if (t < 128) {
    v = btot[t];
    x = v;
    #pragma unroll
    for (int off = 1; off < 64; off <<= 1) {
      int y = __shfl_up(x, off, 64);
      if (lane >= off) x += y;
    }
    if (lane == 63) wtot[t >> 6] = x;
  }
  __syncthreads();
  if (t < 128) {
    int wo = (t >= 64) ? wtot[0] : 0;
    cur[t] = wo + x - v + g[t * NCH + c];  // global offset for (bucket t, chunk c)
  }
  __syncthreads();
  int base = c * CE;
  for (int i = t; i < CE; i += 256) {
    int d = edst[base + i];
    int s = esrc[base + i];
    int p = atomicAdd(&cur[d / BN], 1);
    ebuf[p] = ((uint_t)d << 16) | (uint_t)s;
  }
}

// f4: per-bucket fine fill; also emits rowptr. Redundant bucket-offset scan.
__global__ __launch_bounds__(256) void f4_fill(const uint_t* __restrict__ ebuf,
                                               const int* __restrict__ btot,
                                               int* __restrict__ rowptr,
                                               int* __restrict__ csr_src) {
  __shared__ int cnt[392];
  __shared__ int cur[392];
  __shared__ int sofs[NB];
  __shared__ int wtot[2];
  int b = blockIdx.x, t = threadIdx.x;
  int lane = t & 63;
  int x = 0, v = 0;
  if (t < 128) {
    v = btot[t];
    x = v;
    #pragma unroll
    for (int off = 1; off < 64; off <<= 1) {
      int y = __shfl_up(x, off, 64);
      if (lane >= off) x += y;
    }
    if (lane == 63) wtot[t >> 6] = x;
  }
  __syncthreads();
  if (t < 128) {
    int wo = (t >= 64) ? wtot[0] : 0;
    sofs[t] = wo + x - v;  // exclusive bucket offsets
  }
  __syncthreads();
  int bstart = sofs[b];
  int bend = bstart + btot[b];
  int nbase = b * BN;
  for (int i = t; i < 392; i += 256) cnt[i] = 0;
  __syncthreads();
  for (int i = bstart + t; i < bend; i += 256)
    atomicAdd(&cnt[(ebuf[i] >> 16) - nbase], 1);
  __syncthreads();
  if (t < 64) {  // wave-0 exclusive scan of cnt[0..390]
    int carry = 0;
    for (int base = 0; base < 392; base += 64) {
      int i = base + t;
      int vv = (i < 391) ? cnt[i] : 0;
      int xx = vv;
      #pragma unroll
      for (int off = 1; off < 64; off <<= 1) {
        int y = __shfl_up(xx, off, 64);
        if (t >= off) xx += y;
      }
      if (i < 392) cur[i] = xx - vv + carry;
      carry += __shfl(xx, 63, 64);
    }
  }
  __syncthreads();
  for (int i = t; i < BN; i += 256) {
    int gg = nbase + i;
    if (gg < N_NODES) rowptr[gg] = bstart + cur[i];
  }
  if (b == NB - 1 && t == 0) rowptr[N_NODES] = N_EDGES;
  __syncthreads();
  for (int i = bstart + t; i < bend; i += 256) {
    uint_t pk = ebuf[i];
    int p = atomicAdd(&cur[(pk >> 16) - nbase], 1);
    csr_src[bstart + p] = (int)(pk & 0xffffu);
  }
}

// ---------------- merged: fused SAGE (blocks < gsage) + edge MLP (rest) -----
template <int EFD>
__global__ __launch_bounds__(256) void k_merged(
    // sage args
    const ushort_t* __restrict__ hb,
    const int* __restrict__ rowptr, const int* __restrict__ csr_src,
    const ushort_t* __restrict__ wt, const float* __restrict__ bias,
    ushort_t* __restrict__ out_bf, float* __restrict__ out_f32,
    const ushort_t* __restrict__ wp,
    ushort_t* __restrict__ hub_o, ushort_t* __restrict__ hvb_o,
    int M, int do_relu, int gsage,
    // edge args
    const ushort_t* __restrict__ hub_i, const ushort_t* __restrict__ hvb_i,
    const int* __restrict__ src, const int* __restrict__ dst,
    const float* __restrict__ ef1, const float* __restrict__ ef2,
    const float* __restrict__ we, const float* __restrict__ b,
    const float* __restrict__ w2, const float* __restrict__ b2,
    float* __restrict__ eout, int E) {
  __shared__ ushort_t hs[ROWS][136];
  __shared__ float swe[EFD][EH];
  __shared__ float sw2t[4][EH];
  __shared__ float sb[EH];
  __shared__ float sb2v[4];
  int tid = threadIdx.x;

  if ((int)blockIdx.x >= gsage) {
    // ================= edge part =================
    for (int i = tid; i < EFD * EH; i += 256) swe[i >> 5][i & 31] = we[i];
    if (tid < EH * 4) sw2t[tid & 3][tid >> 2] = w2[tid];
    if (tid < EH) sb[tid] = b[tid];
    if (tid < 4) sb2v[tid] = b2[tid];
    __syncthreads();
    int gi = (blockIdx.x - gsage) * 256 + tid;
    int e = gi >> 2;
    int q = gi & 3;
    if (e >= E) return;
    int s = src[e], d = dst[e];
    int cb = q * 8;
    uint4 au = *(const uint4*)&hub_i[s * EH + cb];
    uint4 av = *(const uint4*)&hvb_i[d * EH + cb];
    float efv[EFD];
    {
      float4 v = *(const float4*)&ef1[(long long)e * 4];
      efv[0] = v.x; efv[1] = v.y; efv[2] = v.z; efv[3] = v.w;
      if constexpr (EFD == 8) {
        float4 v1 = *(const float4*)&ef2[(long long)e * 4];
        efv[4] = v1.x; efv[5] = v1.y; efv[6] = v1.z; efv[7] = v1.w;
      }
    }
    float t[8];
    t[0] = blo(au.x) + blo(av.x) + sb[cb + 0];
    t[1] = bhi(au.x) + bhi(av.x) + sb[cb + 1];
    t[2] = blo(au.y) + blo(av.y) + sb[cb + 2];
    t[3] = bhi(au.y) + bhi(av.y) + sb[cb + 3];
    t[4] = blo(au.z) + blo(av.z) + sb[cb + 4];
    t[5] = bhi(au.z) + bhi(av.z) + sb[cb + 5];
    t[6] = blo(au.w) + blo(av.w) + sb[cb + 6];
    t[7] = bhi(au.w) + bhi(av.w) + sb[cb + 7];
    #pragma unroll
    for (int i = 0; i < EFD; ++i) {
      float efi = efv[i];
      #pragma unroll
      for (int j = 0; j < 8; ++j) t[j] += efi * swe[i][cb + j];
    }
    #pragma unroll
    for (int j = 0; j < 8; ++j) t[j] = fmaxf(t[j], 0.f);
    float o0 = 0.f, o1 = 0.f, o2 = 0.f, o3 = 0.f;
    #pragma unroll
    for (int j = 0; j < 8; ++j) {
      o0 += t[j] * sw2t[0][cb + j];
      o1 += t[j] * sw2t[1][cb + j];
      o2 += t[j] * sw2t[2][cb + j];
      o3 += t[j] * sw2t[3][cb + j];
    }
    #pragma unroll
    for (int m = 2; m; m >>= 1) {
      o0 += __shfl_xor(o0, m, 64);
      o1 += __shfl_xor(o1, m, 64);
      o2 += __shfl_xor(o2, m, 64);
      o3 += __shfl_xor(o3, m, 64);
    }
    if constexpr (EFD == 4) {
      if (q == 0)
        *(float4*)&eout[(long long)e * 4] =
            make_float4(o0 + sb2v[0], o1 + sb2v[1], o2 + sb2v[2], o3 + sb2v[3]);
    } else {
      if (q == 0)
        *(float4*)&eout[(long long)e * 12 + 8] =
            make_float4(o0 + sb2v[0], o1 + sb2v[1], o2 + sb2v[2], o3 + sb2v[3]);
      if (q == 1)
        *(float4*)&eout[(long long)e * 12] =
            make_float4(efv[0], efv[1], efv[2], efv[3]);
      if (q == 2)
        *(float4*)&eout[(long long)e * 12 + 4] =
            make_float4(efv[4], efv[5], efv[6], efv[7]);
    }
    return;
  }

  // ================= sage part =================
  int wave = tid >> 6, lane = tid & 63;
  int l16 = lane & 15, quad = lane >> 4;
  int row0 = blockIdx.x * ROWS;

  // ---- Phase G: 2 rounds x 4 concurrent nodes per wave, 4-deep ILP
  {
    int grp = lane >> 4;   // node slot 0..3
    int l16g = lane & 15;  // 16B chunk within the 256B row
    #pragma unroll
    for (int r = 0; r < 2; ++r) {
      int lr = wave * 8 + r * 4 + grp;  // local row 0..31
      int n = row0 + lr;
      int beg = 0, end = 0;
      if (n < M) { beg = rowptr[n]; end = rowptr[n + 1]; }
      float f[8];
      #pragma unroll
      for (int k = 0; k < 8; ++k) f[k] = 0.f;
      int j = beg;
      for (; j + 4 <= end; j += 4) {  // 4-deep ILP, no cross-lane deps
        int s0 = csr_src[j];
        int s1 = csr_src[j + 1];
        int s2 = csr_src[j + 2];
        int s3 = csr_src[j + 3];
        uint4 a = *(const uint4*)&hb[s0 * NF + l16g * 8];
        uint4 bb = *(const uint4*)&hb[s1 * NF + l16g * 8];
        uint4 c = *(const uint4*)&hb[s2 * NF + l16g * 8];
        uint4 d = *(const uint4*)&hb[s3 * NF + l16g * 8];
        f[0] += blo(a.x) + blo(bb.x) + blo(c.x) + blo(d.x);
        f[1] += bhi(a.x) + bhi(bb.x) + bhi(c.x) + bhi(d.x);
        f[2] += blo(a.y) + blo(bb.y) + blo(c.y) + blo(d.y);
        f[3] += bhi(a.y) + bhi(bb.y) + bhi(c.y) + bhi(d.y);
        f[4] += blo(a.z) + blo(bb.z) + blo(c.z) + blo(d.z);
        f[5] += bhi(a.z) + bhi(bb.z) + bhi(c.z) + bhi(d.z);
        f[6] += blo(a.w) + blo(bb.w) + blo(c.w) + blo(d.w);
        f[7] += bhi(a.w) + bhi(bb.w) + bhi(c.w) + bhi(d.w);
      }
      for (; j < end; ++j) {  // scalar tail
        int s0 = csr_src[j];
        uint4 a = *(const uint4*)&hb[s0 * NF + l16g * 8];
        f[0] += blo(a.x); f[1] += bhi(a.x);
        f[2] += blo(a.y); f[3] += bhi(a.y);
        f[4] += blo(a.z); f[5] += bhi(a.z);
        f[6] += blo(a.w); f[7] += bhi(a.w);
      }
      if (n < M) {
        int deg = end - beg;
        float inv = deg > 0 ? 1.0f / (float)deg : 0.f;
        u16x8 p;
        #pragma unroll
        for (int k = 0; k < 8; ++k) p[k] = f2bf(f[k] * inv);
        *(u16x8*)&hs[lr][l16g * 8] = p;
      }
    }
  }
  __syncthreads();

  // ---- Phase M: MFMA over K=256 ([self(global) | agg(LDS)])
  int n0 = wave * 32;
  f32x4 acc[2][2];
  #pragma unroll
  for (int a = 0; a < 2; ++a)
    #pragma unroll
    for (int b2_ = 0; b2_ < 2; ++b2_) acc[a][b2_] = (f32x4){0.f, 0.f, 0.f, 0.f};

  #pragma unroll
  for (int ks = 0; ks < 8; ++ks) {
    int k0 = ks * 32;
    bf16x8 afr[2];
    #pragma unroll
    for (int mt = 0; mt < 2; ++mt) {
      if (ks < 4) {
        int r = row0 + mt * 16 + l16;
        if (r >= M) r = M - 1;
        afr[mt] = __builtin_bit_cast(bf16x8, *(const u16x8*)&hb[r * NF + k0 + quad * 8]);
      } else {
        afr[mt] = __builtin_bit_cast(bf16x8,
            *(const u16x8*)&hs[mt * 16 + l16][(k0 & 127) + quad * 8]);
      }
    }
    bf16x8 bfr[2];
    #pragma unroll
    for (int nt = 0; nt < 2; ++nt) {
      int n = n0 + nt * 16 + l16;
      bfr[nt] = __builtin_bit_cast(bf16x8, *(const u16x8*)&wt[n * 256 + k0 + quad * 8]);
    }
    #pragma unroll
    for (int mt = 0; mt < 2; ++mt)
      #pragma unroll
      for (int nt = 0; nt < 2; ++nt)
        acc[mt][nt] = __builtin_amdgcn_mfma_f32_16x16x32_bf16(
            afr[mt], bfr[nt], acc[mt][nt], 0, 0, 0);
  }

  if (wp) __syncthreads();  // all waves done reading agg LDS before overwrite

  #pragma unroll
  for (int nt = 0; nt < 2; ++nt) {
    int col = n0 + nt * 16 + l16;
    float bv = bias[col];
    #pragma unroll
    for (int mt = 0; mt < 2; ++mt) {
      #pragma unroll
      for (int reg = 0; reg < 4; ++reg) {
        int lr = mt * 16 + quad * 4 + reg;
        int r = row0 + lr;
        float v = acc[mt][nt][reg] + bv;
        if (do_relu) v = fmaxf(v, 0.f);
        if (r < M) {
          if (out_f32) out_f32[r * NF + col] = v;
          else         out_bf[r * NF + col] = f2bf(v);
        }
        if (wp) hs[lr][col] = f2bf(v);  // rows >= M hold junk; never stored later
      }
    }
  }

  if (wp) {
    __syncthreads();
    int nb2 = wave * 16;
    f32x4 pacc[2];
    #pragma unroll
    for (int a = 0; a < 2; ++a) pacc[a] = (f32x4){0.f, 0.f, 0.f, 0.f};
    #pragma unroll
    for (int ks = 0; ks < 4; ++ks) {
      int k0 = ks * 32;
      bf16x8 bfrp = __builtin_bit_cast(bf16x8,
          *(const u16x8*)&wp[(nb2 + l16) * NF + k0 + quad * 8]);
      #pragma unroll
      for (int mt = 0; mt < 2; ++mt) {
        bf16x8 afr = __builtin_bit_cast(bf16x8,
            *(const u16x8*)&hs[mt * 16 + l16][k0 + quad * 8]);
        pacc[mt] = __builtin_amdgcn_mfma_f32_16x16x32_bf16(afr, bfrp, pacc[mt], 0, 0, 0);
      }
    }
    int col = nb2 + l16;
    #pragma unroll
    for (int mt = 0; mt < 2; ++mt) {
      #pragma unroll
      for (int reg = 0; reg < 4; ++reg) {
        int r = row0 + mt * 16 + quad * 4 + reg;
        if (r < M) {
          ushort_t v = f2bf(pacc[mt][reg]);
          if (col < 32) hub_o[r * EH + col] = v;
          else          hvb_o[r * EH + col - 32] = v;
        }
      }
    }
  }
}

// ---------------- launch ----------------
extern "C" void kernel_launch(void* const* d_in, const int* in_sizes, int n_in,
                              void* d_out, int out_size, void* d_ws, size_t ws_size,
                              hipStream_t stream) {
  const float* inputs    = (const float*)d_in[0];
  const float* edge_feat = (const float*)d_in[1];
  const float* w_self1   = (const float*)d_in[2];
  const float* w_neigh1  = (const float*)d_in[3];
  const float* b_conv1   = (const float*)d_in[4];
  const float* eu1_wu    = (const float*)d_in[5];
  const float* eu1_wv    = (const float*)d_in[6];
  const float* eu1_we    = (const float*)d_in[7];
  const float* eu1_b     = (const float*)d_in[8];
  const float* eu1_w2    = (const float*)d_in[9];
  const float* eu1_b2    = (const float*)d_in[10];
  const float* w_self2   = (const float*)d_in[11];
  const float* w_neigh2  = (const float*)d_in[12];
  const float* b_conv2   = (const float*)d_in[13];
  const float* eu2_wu    = (const float*)d_in[14];
  const float* eu2_wv    = (const float*)d_in[15];
  const float* eu2_we    = (const float*)d_in[16];
  const float* eu2_b     = (const float*)d_in[17];
  const float* eu2_w2    = (const float*)d_in[18];
  const float* eu2_b2    = (const float*)d_in[19];
  const float* w_self3   = (const float*)d_in[20];
  const float* w_neigh3  = (const float*)d_in[21];
  const float* b_conv3   = (const float*)d_in[22];
  const int*   esrc      = (const int*)d_in[23];
  const int*   edst      = (const int*)d_in[24];

  float* out_h  = (float*)d_out;                           // [N,128]
  float* out_ef = (float*)d_out + (long long)N_NODES * NF; // [E,12]

  // workspace: int region then bf16 region
  int* iws     = (int*)d_ws;
  int* gofs    = iws;                 // 32768 (NB*NCH)
  uint_t* ebuf = (uint_t*)(iws + 32768);  // 800000
  int* rowptr  = iws + 832768;        // 50001 (pad 50004) -> ends 882772
  int* csr_src = iws + 882784;        // 800000 -> ends 1682784
  ushort_t* ub = (ushort_t*)(iws + 1682784);  // byte off 6731136, %16==0
  ushort_t* xb   = ub;                        // N*128 = 6.4e6
  ushort_t* hAb  = ub + 6400000;
  ushort_t* hBb  = ub + 12800000;
  // compact eu1 staging [E,4] fp32 in the free ex-aggb slot (12.8MB)
  float* eu1t    = (float*)(ub + 19200000);   // 6.4e6 ushorts = 12.8MB
  ushort_t* wt1  = ub + 25600000;             // 32768 each
  ushort_t* wt2  = ub + 25632768;
  ushort_t* wt3  = ub + 25665536;
  ushort_t* wp1  = ub + 25698304;             // 8192 each
  ushort_t* wp2  = ub + 25706496;             // ends 25714688
  // hu/hv layer1: dedicated (no aliasing — sage2 runs concurrently w/ edge1)
  ushort_t* hub1 = ub + 25714688;             // 1.6e6 each
  ushort_t* hvb1 = ub + 27314688;             // ends 28914688
  int* btot      = (int*)(ub + 30000000);     // 128 ints (bucket totals)
  // hu/hv layer2 alias xb (xb dead after sage1 reads it)
  ushort_t* hub2 = xb;
  ushort_t* hvb2 = xb + (long long)N_NODES * EH;

  const int N = N_NODES, E = N_EDGES;
  int gsage = (N + ROWS - 1) / ROWS;          // 1563
  int gedge = (E * 4) / 256;                  // 12500 exactly
  int gmerged = gsage + gedge;                // 14063

  // ---- prep (+f1 hist), parallel scan, bin, fill
  k_prep<<<448 + 6250 + 256, 256, 0, stream>>>(
      w_self1, w_neigh1, w_self2, w_neigh2, w_self3, w_neigh3,
      eu1_wu, eu1_wv, eu2_wu, eu2_wv,
      wt1, wt2, wt3, wp1, wp2, inputs, xb, edst, gofs);
  f2b_scan<<<NB, 256, 0, stream>>>(gofs, btot);
  f3_bin<<<NCH, 256, 0, stream>>>(esrc, edst, gofs, btot, ebuf);
  f4_fill<<<NB, 256, 0, stream>>>(ebuf, btot, rowptr, csr_src);

  // ---- layer 1 sage (sage-only launch: grid == gsage, edge part idle)
  k_merged<4><<<gsage, 256, 0, stream>>>(
      xb, rowptr, csr_src, wt1, b_conv1, hAb, nullptr, wp1, hub1, hvb1,
      N, 1, gsage,
      nullptr, nullptr, nullptr, nullptr, nullptr, nullptr,
      nullptr, nullptr, nullptr, nullptr, nullptr, 0);

  // ---- edge1 (eu1 -> eu1t) || sage2 (hAb -> hBb, proj -> hub2/hvb2)
  k_merged<4><<<gmerged, 256, 0, stream>>>(
      hAb, rowptr, csr_src, wt2, b_conv2, hBb, nullptr, wp2, hub2, hvb2,
      N, 1, gsage,
      hub1, hvb1, esrc, edst, edge_feat, nullptr,
      eu1_we, eu1_b, eu1_w2, eu1_b2, eu1t, E);

  // ---- edge2 (full out_ef rows) || sage3 (hBb -> out_h fp32, no proj)
  k_merged<8><<<gmerged, 256, 0, stream>>>(
      hBb, rowptr, csr_src, wt3, b_conv3, nullptr, out_h, nullptr, nullptr, nullptr,
      N, 0, gsage,
      hub2, hvb2, esrc, edst, edge_feat, eu1t,
      eu2_we, eu2_b, eu2_w2, eu2_b2, out_ef, E);
}